// Round 14
// baseline (238.984 us; speedup 1.0000x reference)
//
#include <hip/hip_runtime.h>
#include <hip/hip_bf16.h>
#include <stdint.h>

#define T_DIM 8192
#define B_DIM 8
#define D_DIM 512
#define O_DIM 512

typedef __attribute__((ext_vector_type(4))) float f32x4;
typedef __attribute__((ext_vector_type(8))) short short8;
typedef __attribute__((ext_vector_type(4))) unsigned short us4;
typedef __attribute__((ext_vector_type(4))) uint32_t u32x4;

__device__ __forceinline__ unsigned short f2bf(float f) {
  union { float f; uint32_t u; } v; v.f = f;
  uint32_t u = v.u + 0x7FFFu + ((v.u >> 16) & 1u);   // RNE
  return (unsigned short)(u >> 16);
}

__device__ __forceinline__ uint32_t cvtpk(float a, float b) {
  uint32_t r;
  asm("v_cvt_pk_bf16_f32 %0, %1, %2" : "=v"(r) : "v"(a), "v"(b));
  return r;
}

__device__ __forceinline__ void gload_lds16(const void* g, void* l) {
  __builtin_amdgcn_global_load_lds(
      (const __attribute__((address_space(1))) void*)g,
      (__attribute__((address_space(3))) void*)l, 16, 0, 0);
}

__device__ __forceinline__ float clip_lam(const float* decay) {
  return fminf(fmaxf(decay[0], 0.5f), 0.999f);
}

// ---------------------------------------------------------------------------
// Pass 1: h_avg[t][d] = mean_b x[b][t][d].  Batched reads (proven ~22us).
__global__ void mean_kernel(const float* __restrict__ x, float* __restrict__ havg) {
  int idx = blockIdx.x * 256 + threadIdx.x;           // over T*D/4
  const f32x4* x4 = (const f32x4*)x;
  const size_t stride = (size_t)T_DIM * D_DIM / 4;
  f32x4 v[8];
#pragma unroll
  for (int b = 0; b < B_DIM; ++b) v[b] = x4[(size_t)b * stride + idx];
  f32x4 s = ((v[0] + v[1]) + (v[2] + v[3])) + ((v[4] + v[5]) + (v[6] + v[7]));
  s *= 0.125f;
  ((f32x4*)havg)[idx] = s;
}

// ---------------------------------------------------------------------------
// Pass 2: W (2D x O, f32, [k][n]) -> Wt bf16 n-major: Wt[h][n][k]=W[h*512+k][n]
__global__ void wconv_kernel(const float* __restrict__ W, unsigned short* __restrict__ Wt) {
  __shared__ float tile[64][65];
  int bk = blockIdx.x >> 3;
  int bn = blockIdx.x & 7;
  int tr = threadIdx.x >> 4;
  int tc = threadIdx.x & 15;
#pragma unroll
  for (int i = 0; i < 4; ++i) {
    int row = i * 16 + tr;
    f32x4 v = *(const f32x4*)&W[(size_t)(bk * 64 + row) * O_DIM + bn * 64 + tc * 4];
#pragma unroll
    for (int j = 0; j < 4; ++j) tile[row][tc * 4 + j] = v[j];
  }
  __syncthreads();
#pragma unroll
  for (int i = 0; i < 4; ++i) {
    int nl = i * 16 + tr;
    us4 o;
#pragma unroll
    for (int j = 0; j < 4; ++j) o[j] = f2bf(tile[tc * 4 + j][nl]);
    int kg = bk * 64 + tc * 4;
    int h = kg >> 9;
    int k = kg & 511;
    *(us4*)&Wt[(size_t)h * (512 * 512) + (size_t)(bn * 64 + nl) * 512 + k] = o;
  }
}

// ---------------------------------------------------------------------------
// Exact 3-pass chunked EMA scan. CHUNK=128, NCHUNK=64.
#define CHUNK 128
#define NCHUNK (T_DIM / CHUNK)

__global__ void scanA_kernel(float* __restrict__ havg, const float* __restrict__ decay) {
  int chunk = blockIdx.x >> 1;
  int d = ((blockIdx.x & 1) << 8) + threadIdx.x;
  float lam = clip_lam(decay);
  float om = 1.0f - lam;
  size_t base = (size_t)chunk * CHUNK * D_DIM + d;
  float cur[16], nxt[16];
#pragma unroll
  for (int i = 0; i < 16; ++i) cur[i] = havg[base + (size_t)i * D_DIM];
  float s = 0.f;
  for (int blk = 0; blk < 8; ++blk) {
    if (blk < 7) {
#pragma unroll
      for (int i = 0; i < 16; ++i)
        nxt[i] = havg[base + (size_t)((blk + 1) * 16 + i) * D_DIM];
    }
#pragma unroll
    for (int i = 0; i < 16; ++i) {
      s = lam * s + om * cur[i];
      havg[base + (size_t)(blk * 16 + i) * D_DIM] = s;
    }
#pragma unroll
    for (int i = 0; i < 16; ++i) cur[i] = nxt[i];
  }
}

__global__ void scanB_kernel(const float* __restrict__ havg, const float* __restrict__ decay,
                             float* __restrict__ carry) {
  int d = blockIdx.x * 256 + threadIdx.x;
  float lam = clip_lam(decay);
  float l2 = lam * lam;
  float l4 = l2 * l2;
  float l8 = l4 * l4;
  float l16 = l8 * l8;
  float l32 = l16 * l16;
  float l64 = l32 * l32;
  float l128 = l64 * l64;
  float e[NCHUNK];
#pragma unroll
  for (int c = 0; c < NCHUNK; ++c)
    e[c] = havg[((size_t)c * CHUNK + CHUNK - 1) * D_DIM + d];
  float s = 0.f;
#pragma unroll
  for (int c = 0; c < NCHUNK; ++c) {
    s = l128 * s + e[c];
    carry[c * D_DIM + d] = s;
  }
}

__global__ void scanC_kernel(const float* __restrict__ havg, const float* __restrict__ carry,
                             const float* __restrict__ decay, unsigned short* __restrict__ st) {
  int idx = blockIdx.x * 256 + threadIdx.x;
  int t = idx >> 7;
  int d4 = idx & 127;
  int c = t >> 7;
  int k = t & 127;
  float lam = clip_lam(decay);
  float w = exp2f((float)(k + 1) * __log2f(lam));
  f32x4 p = ((const f32x4*)havg)[idx];
  f32x4 cin = {0.f, 0.f, 0.f, 0.f};
  if (c > 0) cin = ((const f32x4*)carry)[(size_t)(c - 1) * 128 + d4];
  us4 o;
#pragma unroll
  for (int j = 0; j < 4; ++j) o[j] = f2bf(p[j] + w * cin[j]);
  ((us4*)st)[idx] = o;
}

// ---------------------------------------------------------------------------
// sbar GEMM (bf16 A = st, proven): dbuf + counted vmcnt(4), 128x128, 4 waves.
__global__ __launch_bounds__(256, 4)
void gemm128bf(const unsigned short* __restrict__ A, const unsigned short* __restrict__ Bt,
               const float* __restrict__ extra, float* __restrict__ C) {
  __shared__ __align__(16) char smem[2][16384];

  int nwg = gridDim.x;
  int bid = blockIdx.x;
  int swz = (bid & 7) * (nwg >> 3) + (bid >> 3);
  int tm = swz >> 2, tn = swz & 3;
  int brow = tm << 7, bcol = tn << 7;

  int tid = threadIdx.x;
  int wave = tid >> 6, lane = tid & 63;
  int wr = (wave >> 1) << 6, wc = (wave & 1) << 6;
  const int lr = lane & 15, lkb = lane >> 4;

  const int soct = ((lane & 3) ^ ((lane >> 3) & 3)) << 3;
  const int pm = (lr >> 1) & 3;

  const size_t a_base = (size_t)(brow + (wave << 4) + (lane >> 2)) * 512 + soct;
  const size_t b_base = (size_t)(bcol + (wave << 4) + (lane >> 2)) * 512 + soct;

  f32x4 acc[4][4];
#pragma unroll
  for (int m = 0; m < 4; ++m)
#pragma unroll
    for (int n = 0; n < 4; ++n) acc[m][n] = (f32x4){0.f, 0.f, 0.f, 0.f};

#define STAGE(buf, kt_)                                                        \
  {                                                                            \
    int k0_ = (kt_) << 5;                                                      \
    _Pragma("unroll")                                                          \
    for (int it = 0; it < 2; ++it)                                             \
      gload_lds16(A + a_base + (size_t)(it << 15) + k0_,                       \
                  &smem[buf][(((it << 2) + wave) << 10)]);                     \
    _Pragma("unroll")                                                          \
    for (int it = 0; it < 2; ++it)                                             \
      gload_lds16(Bt + b_base + (size_t)(it << 15) + k0_,                      \
                  &smem[buf][8192 + (((it << 2) + wave) << 10)]);              \
  }

  STAGE(0, 0);

#pragma unroll 2
  for (int kt = 0; kt < 16; ++kt) {
    const int cur = kt & 1;
    if (kt < 15) {
      STAGE(cur ^ 1, kt + 1);
      asm volatile("s_waitcnt vmcnt(4)" ::: "memory");
    } else {
      asm volatile("s_waitcnt vmcnt(0)" ::: "memory");
    }
    __builtin_amdgcn_s_barrier();
    __builtin_amdgcn_sched_barrier(0);

    const unsigned short* As = (const unsigned short*)&smem[cur][0];
    const unsigned short* Bs = (const unsigned short*)&smem[cur][8192];
    short8 af[4], bfr[4];
#pragma unroll
    for (int m = 0; m < 4; ++m)
      af[m] = *(const short8*)(As + (size_t)(wr + (m << 4) + lr) * 32 + ((lkb ^ pm) << 3));
#pragma unroll
    for (int n = 0; n < 4; ++n)
      bfr[n] = *(const short8*)(Bs + (size_t)(wc + (n << 4) + lr) * 32 + ((lkb ^ pm) << 3));

#pragma unroll
    for (int m = 0; m < 4; ++m)
#pragma unroll
      for (int n = 0; n < 4; ++n)
        acc[m][n] = __builtin_amdgcn_mfma_f32_16x16x32_bf16(af[m], bfr[n], acc[m][n], 0, 0, 0);

    __builtin_amdgcn_sched_barrier(0);
    __builtin_amdgcn_s_barrier();
  }
#undef STAGE

  float* tp = (float*)&smem[0][0] + (size_t)wave * 2048;
#pragma unroll
  for (int m = 0; m < 4; ++m) {
#pragma unroll
    for (int n = 0; n < 4; ++n)
#pragma unroll
      for (int j = 0; j < 4; ++j)
        tp[((lkb << 2) + j) * 68 + (n << 4) + lr] = acc[m][n][j];
    __syncthreads();
#pragma unroll
    for (int p = 0; p < 4; ++p) {
      int rl = (p << 2) + (lane >> 4);
      int c0 = (lane & 15) << 2;
      f32x4 v = *(const f32x4*)(tp + rl * 68 + c0);
      int row = brow + wr + (m << 4) + rl;
      int col = bcol + wc + c0;
      f32x4 e = *(const f32x4*)&extra[col];       // bias
      v += e;
      *(f32x4*)&C[(size_t)row * O_DIM + col] = v;
    }
    __syncthreads();
  }
}

// ---------------------------------------------------------------------------
// MAIN GEMM, direct-to-fragment: out[row][o] = x(f32)[row] @ Wt_h^T + sbar.
// ZERO LDS / ZERO barriers in the K-loop.  Each wave loads its MFMA fragments
// straight from global: A = 2x f32x4 per m (16 lanes x 32B = 16 full 128B
// lines/instr), cvtpk in-register; B = 1x 16B per n from Wt (L2-resident
// 0.5MB).  1-deep register pipeline: load frags(k+1) while MFMA(k).  Waves
// fully independent -> TLP (12 waves/CU) + ILP hides L2/L3 latency (the
// barrier-coupled LDS path plateaued at ~85us across 4 schedule variants).
// LDS (32KB) used only for the epilogue transpose.
__global__ __launch_bounds__(256, 3)
void gemm_direct(const float* __restrict__ X, const unsigned short* __restrict__ Wt,
                 const float* __restrict__ sbar, float* __restrict__ C) {
  __shared__ __align__(16) char smem[32768];

  int nwg = gridDim.x;
  int bid = blockIdx.x;
  int swz = (bid & 7) * (nwg >> 3) + (bid >> 3);
  int tm = swz >> 2, tn = swz & 3;
  int brow = tm << 7, bcol = tn << 7;

  int tid = threadIdx.x;
  int wave = tid >> 6, lane = tid & 63;
  int wr = (wave >> 1) << 6, wc = (wave & 1) << 6;
  const int lr = lane & 15, lkb = lane >> 4;

  // fragment source pointers (k-base lkb*8 folded in; per-step offset = kt*32)
  const float* ax[4];
  const unsigned short* bw[4];
#pragma unroll
  for (int m = 0; m < 4; ++m)
    ax[m] = X + (size_t)(brow + wr + (m << 4) + lr) * 512 + (lkb << 3);
#pragma unroll
  for (int n = 0; n < 4; ++n)
    bw[n] = Wt + (size_t)(bcol + wc + (n << 4) + lr) * 512 + (lkb << 3);

  f32x4 acc[4][4];
#pragma unroll
  for (int m = 0; m < 4; ++m)
#pragma unroll
    for (int n = 0; n < 4; ++n) acc[m][n] = (f32x4){0.f, 0.f, 0.f, 0.f};

  f32x4 a0[4], a1[4];
  short8 bl[4];
#pragma unroll
  for (int m = 0; m < 4; ++m) {
    a0[m] = *(const f32x4*)(ax[m]);
    a1[m] = *(const f32x4*)(ax[m] + 4);
  }
#pragma unroll
  for (int n = 0; n < 4; ++n) bl[n] = *(const short8*)(bw[n]);

  for (int kt = 0; kt < 16; ++kt) {
    // convert current A fragments (waits on this kt's loads only)
    short8 af[4];
#pragma unroll
    for (int m = 0; m < 4; ++m) {
      union { short8 s; u32x4 u; } t;
      t.u = (u32x4){cvtpk(a0[m][0], a0[m][1]), cvtpk(a0[m][2], a0[m][3]),
                    cvtpk(a1[m][0], a1[m][1]), cvtpk(a1[m][2], a1[m][3])};
      af[m] = t.s;
    }
    short8 bf[4];
#pragma unroll
    for (int n = 0; n < 4; ++n) bf[n] = bl[n];

    // issue next-step fragment loads (12 x 16B) before the MFMAs
    if (kt < 15) {
      int off = (kt + 1) << 5;
#pragma unroll
      for (int m = 0; m < 4; ++m) {
        a0[m] = *(const f32x4*)(ax[m] + off);
        a1[m] = *(const f32x4*)(ax[m] + off + 4);
      }
#pragma unroll
      for (int n = 0; n < 4; ++n) bl[n] = *(const short8*)(bw[n] + off);
    }

#pragma unroll
    for (int m = 0; m < 4; ++m)
#pragma unroll
      for (int n = 0; n < 4; ++n)
        acc[m][n] = __builtin_amdgcn_mfma_f32_16x16x32_bf16(af[m], bf[n], acc[m][n], 0, 0, 0);
  }

  // ---- epilogue: per-wave LDS transpose ([16][68] f32), vectorized I/O ----
  float* tp = (float*)smem + (size_t)wave * 2048;    // disjoint 8KB/wave
#pragma unroll
  for (int m = 0; m < 4; ++m) {
#pragma unroll
    for (int n = 0; n < 4; ++n)
#pragma unroll
      for (int j = 0; j < 4; ++j)
        tp[((lkb << 2) + j) * 68 + (n << 4) + lr] = acc[m][n][j];
    __syncthreads();
#pragma unroll
    for (int p = 0; p < 4; ++p) {
      int rl = (p << 2) + (lane >> 4);
      int c0 = (lane & 15) << 2;
      f32x4 v = *(const f32x4*)(tp + rl * 68 + c0);
      int row = brow + wr + (m << 4) + rl;
      int col = bcol + wc + c0;
      f32x4 e = *(const f32x4*)&sbar[(size_t)(row & (T_DIM - 1)) * O_DIM + col];
      v += e;
      *(f32x4*)&C[(size_t)row * O_DIM + col] = v;
    }
    __syncthreads();
  }
}

// ---------------------------------------------------------------------------
extern "C" void kernel_launch(void* const* d_in, const int* in_sizes, int n_in,
                              void* d_out, int out_size, void* d_ws, size_t ws_size,
                              hipStream_t stream) {
  (void)in_sizes; (void)n_in; (void)out_size; (void)ws_size;
  const float* x     = (const float*)d_in[0];   // [8][8192][512]
  const float* W     = (const float*)d_in[1];   // [1024][512]
  const float* bias  = (const float*)d_in[2];   // [512]
  const float* decay = (const float*)d_in[3];   // [1]
  float* out = (float*)d_out;                   // [8][8192][512]

  char* ws = (char*)d_ws;
  size_t off = 0;
  float*          havg  = (float*)(ws + off);          off += 16777216;  // 16 MiB
  unsigned short* st    = (unsigned short*)(ws + off); off += 8388608;   //  8 MiB
  unsigned short* Wt    = (unsigned short*)(ws + off); off += 1048576;   //  1 MiB
  float*          sbar  = (float*)(ws + off);          off += 16777216;  // 16 MiB
  float*          carry = (float*)(ws + off);          off += 131072;    // 128 KiB

  mean_kernel<<<T_DIM * D_DIM / 4 / 256, 256, 0, stream>>>(x, havg);
  wconv_kernel<<<128, 256, 0, stream>>>(W, Wt);
  scanA_kernel<<<NCHUNK * 2, 256, 0, stream>>>(havg, decay);
  scanB_kernel<<<2, 256, 0, stream>>>(havg, decay, carry);
  scanC_kernel<<<T_DIM * D_DIM / 4 / 256, 256, 0, stream>>>(havg, carry, decay, st);
  // sbar[t][o] = states @ W_s + b   (M=8192)
  gemm128bf<<<(T_DIM / 128) * 4, 256, 0, stream>>>(st, Wt + 512 * 512, bias, sbar);
  // out[b*T+t][o] = x @ W_h + sbar[t][o]   (M=65536, direct-to-fragment)
  gemm_direct<<<(B_DIM * T_DIM / 128) * 4, 256, 0, stream>>>(x, Wt, sbar, out);
}